// Round 14
// baseline (589.281 us; speedup 1.0000x reference)
//
#include <hip/hip_runtime.h>
#include <hip/hip_bf16.h>

#define M_DIM 8192
#define N_DIM 11008
#define K_DIM 4096
#define NT 32                        // K-tiles of BK=128 (int8)
#define RROW ((size_t)64 * K_DIM)    // 64 rows of int8, in bytes

typedef __attribute__((ext_vector_type(4))) int i32x4;

// ---------------- per-token activation quant: n = rint(x/s), s = max(absmax,1e-5)/7 ----------------
__global__ void quant_x_kernel(const float* __restrict__ x,
                               char* __restrict__ xq, float* __restrict__ sx) {
  const int row = blockIdx.x;      // 8192
  const int t = threadIdx.x;       // 256
  const float4* xr4 = (const float4*)(x + (size_t)row * K_DIM);
  float4 v[4];
  float amax = 0.0f;
#pragma unroll
  for (int i = 0; i < 4; ++i) {
    v[i] = xr4[t + 256 * i];
    amax = fmaxf(amax, fmaxf(fmaxf(fabsf(v[i].x), fabsf(v[i].y)),
                             fmaxf(fabsf(v[i].z), fabsf(v[i].w))));
  }
#pragma unroll
  for (int off = 32; off > 0; off >>= 1)
    amax = fmaxf(amax, __shfl_xor(amax, off, 64));
  __shared__ float red[4];
  if ((t & 63) == 0) red[t >> 6] = amax;
  __syncthreads();
  amax = fmaxf(fmaxf(red[0], red[1]), fmaxf(red[2], red[3]));
  const float s = fmaxf(amax, 1e-5f) / 7.0f;   // matches reference bitwise
  if (t == 0) sx[row] = s;
  char q[16];
#pragma unroll
  for (int i = 0; i < 4; ++i) {
    q[i * 4 + 0] = (char)(int)rintf(v[i].x / s);  // RNE, exact ints in [-7,7]
    q[i * 4 + 1] = (char)(int)rintf(v[i].y / s);
    q[i * 4 + 2] = (char)(int)rintf(v[i].z / s);
    q[i * 4 + 3] = (char)(int)rintf(v[i].w / s);
  }
  *(int4*)(xq + (size_t)row * K_DIM + t * 16) = *(int4*)q;
}

// ---------------- per-output-channel weight quant: int8 / 127 (row-major) ----------------
__global__ void quant_w_kernel(const float* __restrict__ w,
                               char* __restrict__ wq, float* __restrict__ sw) {
  const int row = blockIdx.x;      // 11008
  const int t = threadIdx.x;       // 256
  const float4* wr4 = (const float4*)(w + (size_t)row * K_DIM);
  float4 v[4];
  float amax = 0.0f;
#pragma unroll
  for (int i = 0; i < 4; ++i) {
    v[i] = wr4[t + 256 * i];
    amax = fmaxf(amax, fmaxf(fmaxf(fabsf(v[i].x), fabsf(v[i].y)),
                             fmaxf(fabsf(v[i].z), fabsf(v[i].w))));
  }
#pragma unroll
  for (int off = 32; off > 0; off >>= 1)
    amax = fmaxf(amax, __shfl_xor(amax, off, 64));
  __shared__ float red[4];
  if ((t & 63) == 0) red[t >> 6] = amax;
  __syncthreads();
  amax = fmaxf(fmaxf(red[0], red[1]), fmaxf(red[2], red[3]));
  const float s = fmaxf(amax, 1e-30f) / 127.0f;
  if (t == 0) sw[row] = s;
  char q[16];
#pragma unroll
  for (int i = 0; i < 4; ++i) {
    q[i * 4 + 0] = (char)(int)rintf(v[i].x / s);  // in [-127,127]
    q[i * 4 + 1] = (char)(int)rintf(v[i].y / s);
    q[i * 4 + 2] = (char)(int)rintf(v[i].z / s);
    q[i * 4 + 3] = (char)(int)rintf(v[i].w / s);
  }
  *(int4*)(wq + (size_t)row * K_DIM + t * 16) = *(int4*)q;
}

// ---------------- GEMM ----------------
// 128x128 tile, BK=128 int8, 512 thr (8 waves 2x4), per-wave output 64x32
// (acc = 32 VGPR). LDS 64 KiB dbuf -> 2 blocks/CU, 16 waves/CU = 4 waves/SIMD:
// each wave's ~216-cyc LDS cluster latency is covered by 3 sibling MFMA bursts
// + an independent second barrier group (the occupancy every 256^2 variant
// lacked). __launch_bounds__(512,4) caps 128 VGPR (audit: ~100 used).
// Swizzle (verified 0 conflicts): phys = row*128 + (col ^ ((row&7)<<4)),
// staged via inverse-swizzled global source (linear gload_lds dest).
#define GL(g, d)                                                             \
  __builtin_amdgcn_global_load_lds(                                          \
      (const __attribute__((address_space(1))) void*)(g),                    \
      (__attribute__((address_space(3))) void*)(d), 16, 0, 0)

#define MFMA_I8 __builtin_amdgcn_mfma_i32_16x16x64_i8

template<bool STG>
__device__ __forceinline__ void tile_body(const char* paRow, const char* pbRow,
    int colswz, const char* gA1, char* dA1, const char* gB1, char* dB1,
    i32x4 (&acc)[4][2]) {
  __syncthreads();   // tile t staged (drains vmcnt); prev-buffer readers done
  if constexpr (STG) {  // stage tile t+1 into the other buffer (4 x 8KB loads)
    GL(gA1, dA1);  GL(gA1 + RROW, dA1 + 8192);
    GL(gB1, dB1);  GL(gB1 + RROW, dB1 + 8192);
  }
  const int c0 = colswz, c1 = colswz ^ 64;
  i32x4 a0[4], b0[2], a1[4], b1[2];
  // seg1: k0 reads
#pragma unroll
  for (int n = 0; n < 2; ++n) b0[n] = *(const i32x4*)(pbRow + n * 2048 + c0);
#pragma unroll
  for (int m = 0; m < 4; ++m) a0[m] = *(const i32x4*)(paRow + m * 2048 + c0);
  __builtin_amdgcn_sched_barrier(0);
  // seg2: k1 reads || MFMA k0
#pragma unroll
  for (int n = 0; n < 2; ++n) b1[n] = *(const i32x4*)(pbRow + n * 2048 + c1);
#pragma unroll
  for (int m = 0; m < 4; ++m) a1[m] = *(const i32x4*)(paRow + m * 2048 + c1);
#pragma unroll
  for (int m = 0; m < 4; ++m)
#pragma unroll
    for (int n = 0; n < 2; ++n)
      acc[m][n] = MFMA_I8(a0[m], b0[n], acc[m][n], 0, 0, 0);
  __builtin_amdgcn_sched_barrier(0);
  // seg3: MFMA k1
#pragma unroll
  for (int m = 0; m < 4; ++m)
#pragma unroll
    for (int n = 0; n < 2; ++n)
      acc[m][n] = MFMA_I8(a1[m], b1[n], acc[m][n], 0, 0, 0);
}

__global__ __launch_bounds__(512, 4) void gemm_kernel(
    const char* __restrict__ xq, const char* __restrict__ wq,
    const float* __restrict__ sx, const float* __restrict__ sw,
    const float* __restrict__ bias, float* __restrict__ out) {
  __shared__ char lds_c[65536];  // A: [0,32K) bufs 16K x2; B: [32K,64K) bufs 16K x2

  const int tid = threadIdx.x;
  const int lane = tid & 63;
  const int wave = tid >> 6;      // 0..7
  const int wm = wave >> 2;       // 0..1 -> 64-row half
  const int wn = wave & 3;        // 0..3 -> 32-col slice
  const int lr = lane & 15;

  // bm-fastest bijective XCD swizzle (5504 = 8*688): the ~64 co-resident blocks
  // of an XCD share one 512 KB B-panel (L2-hot); A panels stream via L3 (75 MB
  // working set fully L3-resident).
  const int bid = blockIdx.x;
  const int sw_id = (bid & 7) * 688 + (bid >> 3);
  const int bm = sw_id & 63, bn = sw_id >> 6;
  const int m0 = bm * 128, n0 = bn * 128;

  // staging source (inverse swizzle, rule #21): row tid>>3 (0..63),
  // source colbyte = phys ^ ((row&7)<<4)
  const int srow = tid >> 3;
  const int srccb = ((tid & 7) << 4) ^ ((srow & 7) << 4);
  const char* gA0 = xq + (size_t)(m0 + srow) * K_DIM + srccb;
  const char* gB0 = wq + (size_t)(n0 + srow) * K_DIM + srccb;
  char* dA0 = lds_c + wave * 1024;            // wave-uniform; HW adds lane*16
  char* dB0 = lds_c + 32768 + wave * 1024;

  // read-side bases (swizzled)
  const int aRowOff = (wm * 64 + lr) * 128;
  const int bRowOff = (wn * 32 + lr) * 128;
  const int colswz = ((lane >> 4) << 4) ^ ((lr & 7) << 4);

  i32x4 acc[4][2] = {};

  // prologue: stage tile 0 into buf 0
  GL(gA0, dA0);  GL(gA0 + RROW, dA0 + 8192);
  GL(gB0, dB0);  GL(gB0 + RROW, dB0 + 8192);

  for (int t = 0; t < NT - 1; ++t) {
    const int buf = t & 1;
    tile_body<true>(lds_c + buf * 16384 + aRowOff,
                    lds_c + 32768 + buf * 16384 + bRowOff, colswz,
                    gA0 + (size_t)(t + 1) * 128, dA0 + (1 - buf) * 16384,
                    gB0 + (size_t)(t + 1) * 128, dB0 + (1 - buf) * 16384, acc);
  }
  tile_body<false>(lds_c + ((NT - 1) & 1) * 16384 + aRowOff,
                   lds_c + 32768 + ((NT - 1) & 1) * 16384 + bRowOff, colswz,
                   nullptr, nullptr, nullptr, nullptr, acc);

  // epilogue: C/D layout col=lane&15, row=(lane>>4)*4+reg (dtype-independent)
  const int orow0 = m0 + wm * 64 + (lane >> 4) * 4;
  const int ocol0 = n0 + wn * 32 + lr;
  float bv[2], swv[2];
#pragma unroll
  for (int fc = 0; fc < 2; ++fc) {
    bv[fc] = bias[ocol0 + fc * 16];
    swv[fc] = sw[ocol0 + fc * 16];
  }
#pragma unroll
  for (int fr = 0; fr < 4; ++fr) {
#pragma unroll
    for (int j = 0; j < 4; ++j) {
      const int grow = orow0 + fr * 16 + j;
      const float s = sx[grow];
      float* op = out + (size_t)grow * N_DIM + ocol0;
#pragma unroll
      for (int fc = 0; fc < 2; ++fc)
        op[fc * 16] = (float)acc[fr][fc][j] * (s * swv[fc]) + bv[fc];
    }
  }
}

extern "C" void kernel_launch(void* const* d_in, const int* in_sizes, int n_in,
                              void* d_out, int out_size, void* d_ws, size_t ws_size,
                              hipStream_t stream) {
  (void)in_sizes; (void)n_in; (void)out_size; (void)ws_size;
  const float* x = (const float*)d_in[0];       // [4,2048,4096] f32
  const float* w = (const float*)d_in[1];       // [11008,4096] f32
  const float* bias = (const float*)d_in[2];    // [1,11008] f32
  float* out = (float*)d_out;                   // [8192,11008] f32

  char* ws = (char*)d_ws;
  float* sx = (float*)ws;                                   // 32 KiB
  float* sw = (float*)(ws + 32768);                         // 44 KiB
  char* xq8 = ws + 131072;                                  // 32 MiB int8
  char* wq8 = ws + 131072 + (size_t)M_DIM * K_DIM;          // 43 MiB int8

  quant_x_kernel<<<M_DIM, 256, 0, stream>>>(x, xq8, sx);
  quant_w_kernel<<<N_DIM, 256, 0, stream>>>(w, wq8, sw);
  gemm_kernel<<<dim3((M_DIM / 128) * (N_DIM / 128)), 512, 0, stream>>>(xq8, wq8, sx, sw, bias, out);
}